// Round 14
// baseline (182.642 us; speedup 1.0000x reference)
//
#include <hip/hip_runtime.h>
#include <hip/hip_bf16.h>
#include <stdint.h>

// y[m,o] = (sum_k x[m,k]*w_int8[o,k]) * scales[o] + bias[o]
// M=2048, N=11008, K=4096.
// Round 14 (= r13 race-fixed): 128x256 block, 4 waves x 128x64 wave-tile,
// BK=64, triple-buffered 72KB LDS, 2 independent blocks/CU, grid 688.
// Per tile t: {afB reads(cur); phaseA MFMA; stage t+2; vmcnt(6) [retires
// t+1's stages, ~1 iter old]; BAR; NXT reads (t+1, now landed); phaseB MFMA}.
// r13's bug: NXT reads preceded any wait on t+1's staging -> read mid-stage.

typedef __attribute__((ext_vector_type(8))) short short8;
typedef __attribute__((ext_vector_type(4))) float f32x4;
typedef __attribute__((ext_vector_type(4))) float float4v;
typedef __attribute__((ext_vector_type(4))) int int4v;

#define MM 2048
#define NN 11008
#define KK 4096
#define NT (KK / 64)           // 64 K-tiles of BK=64 (i8) = 64 B rows
#define ROWB ((size_t)KK)      // 4096 bytes per row (K in i8)

static __device__ __forceinline__ ushort f2bf_rne(float f) {
    uint32_t u = __builtin_bit_cast(uint32_t, f);
    u = (u + 0x7FFFu + ((u >> 16) & 1u)) >> 16;
    return (ushort)u;
}
static __device__ __forceinline__ ushort i2bf_exact(int v) {
    return (ushort)(__builtin_bit_cast(uint32_t, (float)v) >> 16);
}
static __device__ __forceinline__ void gload16(const void* g, void* lds) {
    __builtin_amdgcn_global_load_lds(
        (const __attribute__((address_space(1))) uint32_t*)g,
        (__attribute__((address_space(3))) uint32_t*)lds, 16, 0, 0);
}

#define BAR() do { asm volatile("" ::: "memory"); __builtin_amdgcn_s_barrier(); asm volatile("" ::: "memory"); } while (0)

// ---------------- pass 1: per-row absmax of x -> s_r, 1/s_r ----------------
__global__ __launch_bounds__(256)
void rowmax_x(const float* __restrict__ X, float* __restrict__ Sx, float* __restrict__ SxInv) {
    const int r = blockIdx.x;
    const float4v* xr = (const float4v*)(X + (size_t)r * KK);
    float m = 0.f;
    for (int i = threadIdx.x; i < KK / 4; i += 256) {
        float4v v = xr[i];
        m = fmaxf(m, fmaxf(fmaxf(fabsf(v[0]), fabsf(v[1])),
                           fmaxf(fabsf(v[2]), fabsf(v[3]))));
    }
#pragma unroll
    for (int off = 32; off; off >>= 1) m = fmaxf(m, __shfl_down(m, off));
    __shared__ float wmax[4];
    if ((threadIdx.x & 63) == 0) wmax[threadIdx.x >> 6] = m;
    __syncthreads();
    if (threadIdx.x == 0) {
        float a = fmaxf(fmaxf(wmax[0], wmax[1]), fmaxf(wmax[2], wmax[3]));
        Sx[r]    = a / 127.f;
        SxInv[r] = (a > 0.f) ? 127.f / a : 0.f;
    }
}

// ---------------- pass 2: quantize x -> i8, pack w int32 -> i8 (row-major) ----
__global__ __launch_bounds__(256)
void quant_pack(const float* __restrict__ X, const int* __restrict__ W,
                const float* __restrict__ SxInv,
                char* __restrict__ Xq, char* __restrict__ Wq) {
    const int NX4 = MM * KK / 4;
    const int NW4 = NN * KK / 4;
    const int stride = gridDim.x * blockDim.x;
    for (int i = blockIdx.x * blockDim.x + threadIdx.x; i < NX4 + NW4; i += stride) {
        if (i < NX4) {
            float4v v = ((const float4v*)X)[i];
            const float inv = SxInv[i >> 10];
            uint32_t p = 0;
#pragma unroll
            for (int j = 0; j < 4; ++j) {
                int q = (int)rintf(v[j] * inv);
                p |= ((uint32_t)(q & 255)) << (8 * j);
            }
            ((uint32_t*)Xq)[i] = p;
        } else {
            int j = i - NX4;
            int4v w = ((const int4v*)W)[j];
            uint32_t p = ((uint32_t)(w[0] & 255)) | ((uint32_t)(w[1] & 255) << 8) |
                         ((uint32_t)(w[2] & 255) << 16) | ((uint32_t)(w[3] & 255) << 24);
            ((uint32_t*)Wq)[j] = p;
        }
    }
}

// staging with 256 threads: one gload16 issue = 4 KB = 64 rows x 64 B.
// A tile = 128 rows = 2 issues; B tile = 256 rows = 4 issues. (6 total/tile)
static __device__ __forceinline__ void stageA(const char* g, char* lds, int wid, size_t kb) {
    gload16(g + kb,                      lds        + wid * 1024);
    gload16(g + kb + (size_t)64 * ROWB,  lds + 4096 + wid * 1024);
}
static __device__ __forceinline__ void stageB(const char* g, char* lds, int wid, size_t kb) {
#pragma unroll
    for (int c = 0; c < 4; ++c)
        gload16(g + kb + (size_t)(c * 64) * ROWB, lds + c * 4096 + wid * 1024);
}

// -------- main GEMM: 128x256 block-tile, 4 waves x 128x64, BK=64, pipelined --------
__global__ __launch_bounds__(256, 2)
void gemm_i8(const char* __restrict__ A, const char* __restrict__ B,
             const float* __restrict__ Sx, const float* __restrict__ S,
             const float* __restrict__ Bv, float* __restrict__ Y) {
    __shared__ char smem[73728];          // A0|A1|A2 (8K each) + B0|B1|B2 (16K each)

    const int tid  = threadIdx.x;
    const int lane = tid & 63;
    const int wid  = tid >> 6;            // 4 waves; wave = 128(M) x 64(N), cols wid*64
    const int l15  = lane & 15;
    const int q    = lane >> 4;           // k-chunk 0..3 (16 i8 each)

    // XCD-aware bijective swizzle: 688 = 8 * 86
    const int swz  = (blockIdx.x & 7) * 86 + (blockIdx.x >> 3);
    const int brow = (swz / 43) * 128;    // 16 M-tiles
    const int bcol = (swz % 43) * 256;    // 43 N-tiles

    // staging source: thread covers row (tid>>2) of each 64-row chunk,
    // 16-B slot (tid&3), inverse-swizzled by row parity (r7-verified)
    const int srow4 = tid >> 2;                       // 0..63
    const int sslot = (tid & 3) ^ ((srow4 >> 1) & 3);
    const char* gA = A + (size_t)(brow + srow4) * ROWB + sslot * 16;
    const char* gB = B + (size_t)(bcol + srow4) * ROWB + sslot * 16;

    // ds_read offsets: 64-B rows; swizzled k-slot (r7-verified 0-conflict)
    const int kq  = (q ^ ((l15 >> 1) & 3)) * 16;
    const int rdA = l15 * 64;                          // + m*1024, m=0..7
    const int rdB = (wid * 64 + l15) * 64;             // + n*1024, n=0..3

#define LDA(buf, m) (*(const int4v*)((buf) + rdA + (m) * 1024 + kq))
#define LDB(buf, n) (*(const int4v*)((buf) + rdB + (n) * 1024 + kq))

    int4v acc[8][4] = {};
    int4v afA_a[4], afA_b[4], bf_a[4], bf_b[4], afB[4];

    // rotating named LDS buffer pointers (no pointer array -> compiles clean)
    char* cA = smem;              char* cB = smem + 24576;
    char* nA = smem + 8192;       char* nB = smem + 40960;
    char* pA = smem + 16384;      char* pB = smem + 57344;

    // prologue: stage tile0 -> cur, tile1 -> nxt (6 issues each); retire tile0
    stageA(gA, cA, wid, 0);
    stageB(gB, cB, wid, 0);
    stageA(gA, nA, wid, 64);
    stageB(gB, nB, wid, 64);
    asm volatile("s_waitcnt vmcnt(6)" ::: "memory");
    BAR();
#pragma unroll
    for (int m = 0; m < 4; ++m) afA_a[m] = LDA(cA, m);
#pragma unroll
    for (int n = 0; n < 4; ++n) bf_a[n]  = LDB(cB, n);

    // Per tile t (CUR frags {afA, bf} preloaded):
    //   afB reads (cur m4..7); phase A MFMA (covers them);
    //   stage t+2 -> pA/pB; vmcnt(6) retires t+1's stages (issued last iter,
    //   ~650 cyc old -> near-free), leaves t+2's 6 in flight; BAR makes t+1
    //   visible across waves; NXT reads (tile t+1); phase B MFMA (covers them).
#define GEMM_ITER(AFAc, BFc, AFAn, BFn, T)                                        \
    {                                                                             \
        const int tt = (T);                                                       \
        const size_t kb2 = (size_t)((tt + 2 < NT) ? tt + 2 : NT - 1) * 64;        \
        _Pragma("unroll")                                                         \
        for (int m = 0; m < 4; ++m) afB[m] = LDA(cA, m + 4);                      \
        __builtin_amdgcn_s_setprio(1);                                            \
        _Pragma("unroll")                                                         \
        for (int m = 0; m < 4; ++m)                                               \
            _Pragma("unroll")                                                     \
            for (int n = 0; n < 4; ++n)                                           \
                acc[m][n] = __builtin_amdgcn_mfma_i32_16x16x64_i8(AFAc[m], BFc[n], acc[m][n], 0, 0, 0); \
        __builtin_amdgcn_s_setprio(0);                                            \
        stageA(gA, pA, wid, kb2);                                                 \
        stageB(gB, pB, wid, kb2);                                                 \
        asm volatile("s_waitcnt vmcnt(6)" ::: "memory");                          \
        BAR();                                                                    \
        _Pragma("unroll")                                                         \
        for (int m = 0; m < 4; ++m) AFAn[m] = LDA(nA, m);                         \
        _Pragma("unroll")                                                         \
        for (int n = 0; n < 4; ++n) BFn[n]  = LDB(nB, n);                         \
        __builtin_amdgcn_s_setprio(1);                                            \
        _Pragma("unroll")                                                         \
        for (int m = 0; m < 4; ++m)                                               \
            _Pragma("unroll")                                                     \
            for (int n = 0; n < 4; ++n)                                           \
                acc[m + 4][n] = __builtin_amdgcn_mfma_i32_16x16x64_i8(afB[m], BFc[n], acc[m + 4][n], 0, 0, 0); \
        __builtin_amdgcn_s_setprio(0);                                            \
        { char* t0 = cA; cA = nA; nA = pA; pA = t0;                               \
          char* t1 = cB; cB = nB; nB = pB; pB = t1; }                             \
    }

    for (int t = 0; t < NT; t += 2) {
        GEMM_ITER(afA_a, bf_a, afA_b, bf_b, t);
        GEMM_ITER(afA_b, bf_b, afA_a, bf_a, t + 1);
    }
#undef GEMM_ITER

    // epilogue: y = acc * (s_r[row] * scale[col]) + bias[col]
    // C/D: col = lane&15 (+n*16 + wid*64), row = q*4 + r (+m*16)
#pragma unroll
    for (int n = 0; n < 4; ++n) {
        const int gc = bcol + wid * 64 + n * 16 + l15;
        const float sj = S[gc];
        const float bj = Bv[gc];
#pragma unroll
        for (int m = 0; m < 8; ++m) {
            const int grow = brow + m * 16 + q * 4;
            float* yp = Y + (size_t)grow * NN + gc;
#pragma unroll
            for (int r = 0; r < 4; ++r)
                yp[(size_t)r * NN] = (float)acc[m][n][r] * (Sx[grow + r] * sj) + bj;
        }
    }
#undef LDA
#undef LDB
}

// ---------------- fallback (fused bf16 kernel, no ws needed) ----------------
#define BMF 128
#define BKF 32
#define LDW (BKF + 8)
__global__ __launch_bounds__(256, 2)
void int8lin_fused(const float* __restrict__ X, const int* __restrict__ W,
                   const float* __restrict__ S, const float* __restrict__ Bv,
                   float* __restrict__ Y) {
    __shared__ ushort As[BMF][LDW];
    __shared__ ushort Bs[BMF][LDW];
    const int tid = threadIdx.x, lane = tid & 63, wid = tid >> 6;
    const int wm = wid >> 1, wn = wid & 1, l15 = lane & 15, kh = (lane >> 4) * 8;
    const int bm = blockIdx.x & 15, bn = blockIdx.x >> 4;
    const int brow = bm * BMF, bcol = bn * BMF;
    const int srow = tid >> 1, scol = (tid & 1) * 16;
    const float* xg = X + (size_t)(brow + srow) * KK + scol;
    const int*   wg = W + (size_t)(bcol + srow) * KK + scol;
    f32x4 acc[4][4] = {};
    for (int kt = 0; kt < KK / BKF; ++kt) {
        float4v x0 = *(const float4v*)(xg + 0), x1 = *(const float4v*)(xg + 4);
        float4v x2 = *(const float4v*)(xg + 8), x3 = *(const float4v*)(xg + 12);
        int4v w0 = *(const int4v*)(wg + 0), w1 = *(const int4v*)(wg + 4);
        int4v w2 = *(const int4v*)(wg + 8), w3 = *(const int4v*)(wg + 12);
        xg += BKF; wg += BKF;
        short8 xa = { (short)f2bf_rne(x0[0]), (short)f2bf_rne(x0[1]), (short)f2bf_rne(x0[2]), (short)f2bf_rne(x0[3]),
                      (short)f2bf_rne(x1[0]), (short)f2bf_rne(x1[1]), (short)f2bf_rne(x1[2]), (short)f2bf_rne(x1[3]) };
        short8 xb = { (short)f2bf_rne(x2[0]), (short)f2bf_rne(x2[1]), (short)f2bf_rne(x2[2]), (short)f2bf_rne(x2[3]),
                      (short)f2bf_rne(x3[0]), (short)f2bf_rne(x3[1]), (short)f2bf_rne(x3[2]), (short)f2bf_rne(x3[3]) };
        short8 wa = { (short)i2bf_exact(w0[0]), (short)i2bf_exact(w0[1]), (short)i2bf_exact(w0[2]), (short)i2bf_exact(w0[3]),
                      (short)i2bf_exact(w1[0]), (short)i2bf_exact(w1[1]), (short)i2bf_exact(w1[2]), (short)i2bf_exact(w1[3]) };
        short8 wb = { (short)i2bf_exact(w2[0]), (short)i2bf_exact(w2[1]), (short)i2bf_exact(w2[2]), (short)i2bf_exact(w2[3]),
                      (short)i2bf_exact(w3[0]), (short)i2bf_exact(w3[1]), (short)i2bf_exact(w3[2]), (short)i2bf_exact(w3[3]) };
        __syncthreads();
        *(short8*)&As[srow][scol] = xa; *(short8*)&As[srow][scol + 8] = xb;
        *(short8*)&Bs[srow][scol] = wa; *(short8*)&Bs[srow][scol + 8] = wb;
        __syncthreads();
        short8 af2[4], bf4[4];
#pragma unroll
        for (int i = 0; i < 4; ++i) af2[i] = *(const short8*)&As[wm * 64 + i * 16 + l15][kh];
#pragma unroll
        for (int j = 0; j < 4; ++j) bf4[j] = *(const short8*)&Bs[wn * 64 + j * 16 + l15][kh];
#pragma unroll
        for (int i = 0; i < 4; ++i)
#pragma unroll
            for (int j = 0; j < 4; ++j)
                acc[i][j] = __builtin_amdgcn_mfma_f32_16x16x32_bf16(af2[i], bf4[j], acc[i][j], 0, 0, 0);
    }
#pragma unroll
    for (int j = 0; j < 4; ++j) {
        const int gc = bcol + wn * 64 + j * 16 + l15;
        const float sj = S[gc], bj = Bv[gc];
#pragma unroll
        for (int i = 0; i < 4; ++i) {
            const int grow = brow + wm * 64 + i * 16 + (lane >> 4) * 4;
            float* yp = Y + (size_t)grow * NN + gc;
#pragma unroll
            for (int r = 0; r < 4; ++r)
                yp[(size_t)r * NN] = acc[i][j][r] * sj + bj;
        }
    }
}

extern "C" void kernel_launch(void* const* d_in, const int* in_sizes, int n_in,
                              void* d_out, int out_size, void* d_ws, size_t ws_size,
                              hipStream_t stream) {
    const float* x = (const float*)d_in[0];
    const int*   w = (const int*)d_in[1];
    const float* s = (const float*)d_in[2];
    const float* b = (const float*)d_in[3];
    float* y = (float*)d_out;

    const size_t wq_b = (size_t)NN * KK;            // 45.1 MB
    const size_t xq_b = (size_t)MM * KK;            // 8.4 MB
    const size_t need = wq_b + xq_b + 2 * MM * sizeof(float) + 256;
    if (ws_size >= need) {
        char*  Wq    = (char*)d_ws;
        char*  Xq    = Wq + wq_b;
        float* Sx    = (float*)(Xq + xq_b);
        float* SxInv = Sx + MM;
        hipLaunchKernelGGL(rowmax_x,   dim3(MM),   dim3(256), 0, stream, x, Sx, SxInv);
        hipLaunchKernelGGL(quant_pack, dim3(4096), dim3(256), 0, stream, x, w, SxInv, Xq, Wq);
        hipLaunchKernelGGL(gemm_i8, dim3((MM / 128) * (NN / 256)), dim3(256), 0, stream,
                           Xq, Wq, Sx, s, b, y);
    } else {
        hipLaunchKernelGGL(int8lin_fused, dim3((MM / BMF) * (NN / BMF)), dim3(256), 0, stream,
                           x, w, s, b, y);
    }
}

// Round 15
// 155.501 us; speedup vs baseline: 1.1745x; 1.1745x over previous
//
#include <hip/hip_runtime.h>
#include <hip/hip_bf16.h>
#include <stdint.h>

// y[m,o] = (sum_k x[m,k]*w_int8[o,k]) * scales[o] + bias[o]
// M=2048, N=11008, K=4096.
// Round 15: GEMM = r10 verbatim (verified best: 256x128 tile, 8 waves x 64x64,
// BK=64 i8, triple-buffered 72KB LDS, 2 blocks/CU, 1 barrier/tile, vmcnt(3),
// perfect greedy packing at 118us). Pre-pass fused into ONE kernel:
// blocks 0..2047 own one x-row each (read row into regs -> block max-reduce ->
// quantize from regs; x read ONCE), blocks 2048+ grid-stride the W int32->i8
// pack. Saves the rowmax launch + a full re-read of x (~6-8us).

typedef __attribute__((ext_vector_type(8))) short short8;
typedef __attribute__((ext_vector_type(4))) float f32x4;
typedef __attribute__((ext_vector_type(4))) float float4v;
typedef __attribute__((ext_vector_type(4))) int int4v;

#define MM 2048
#define NN 11008
#define KK 4096
#define NT (KK / 64)           // 64 K-tiles of BK=64 (i8) = 64 B rows
#define ROWB ((size_t)KK)      // 4096 bytes per row (K in i8)
#define PREP_XBLKS MM          // one block per x row
#define PREP_WBLKS 8192

static __device__ __forceinline__ ushort f2bf_rne(float f) {
    uint32_t u = __builtin_bit_cast(uint32_t, f);
    u = (u + 0x7FFFu + ((u >> 16) & 1u)) >> 16;
    return (ushort)u;
}
static __device__ __forceinline__ ushort i2bf_exact(int v) {
    return (ushort)(__builtin_bit_cast(uint32_t, (float)v) >> 16);
}
static __device__ __forceinline__ void gload16(const void* g, void* lds) {
    __builtin_amdgcn_global_load_lds(
        (const __attribute__((address_space(1))) uint32_t*)g,
        (__attribute__((address_space(3))) uint32_t*)lds, 16, 0, 0);
}

#define BAR() do { asm volatile("" ::: "memory"); __builtin_amdgcn_s_barrier(); asm volatile("" ::: "memory"); } while (0)

static __device__ __forceinline__ uint32_t quant4(float4v v, float inv) {
    uint32_t p = 0;
#pragma unroll
    for (int j = 0; j < 4; ++j) {
        int q = (int)rintf(v[j] * inv);
        p |= ((uint32_t)(q & 255)) << (8 * j);
    }
    return p;
}

// ---------------- fused prep: x rowmax+quant (x read once) + W pack ----------------
__global__ __launch_bounds__(256)
void prep(const float* __restrict__ X, const int* __restrict__ W,
          float* __restrict__ Sx, char* __restrict__ Xq, char* __restrict__ Wq) {
    if (blockIdx.x < PREP_XBLKS) {
        // one block per x row: load 4096 floats into regs (16/thread), reduce, quantize
        const int r = blockIdx.x;
        const float4v* xr = (const float4v*)(X + (size_t)r * KK);
        const int t = threadIdx.x;
        float4v v0 = xr[t];
        float4v v1 = xr[t + 256];
        float4v v2 = xr[t + 512];
        float4v v3 = xr[t + 768];
        float m = 0.f;
#pragma unroll
        for (int j = 0; j < 4; ++j) {
            m = fmaxf(m, fmaxf(fabsf(v0[j]), fabsf(v1[j])));
            m = fmaxf(m, fmaxf(fabsf(v2[j]), fabsf(v3[j])));
        }
#pragma unroll
        for (int off = 32; off; off >>= 1) m = fmaxf(m, __shfl_down(m, off));
        __shared__ float wmax[4];
        __shared__ float sinv;
        if ((t & 63) == 0) wmax[t >> 6] = m;
        __syncthreads();
        if (t == 0) {
            float a = fmaxf(fmaxf(wmax[0], wmax[1]), fmaxf(wmax[2], wmax[3]));
            Sx[r] = a / 127.f;
            sinv  = (a > 0.f) ? 127.f / a : 0.f;
        }
        __syncthreads();
        const float inv = sinv;
        uint32_t* xo = (uint32_t*)Xq + (size_t)r * (KK / 4);
        xo[t]       = quant4(v0, inv);
        xo[t + 256] = quant4(v1, inv);
        xo[t + 512] = quant4(v2, inv);
        xo[t + 768] = quant4(v3, inv);
    } else {
        // W pack: int32 -> i8, grid-stride over 4-elem chunks
        const int NW4 = NN * KK / 4;
        const int stride = PREP_WBLKS * 256;
        for (int i = (blockIdx.x - PREP_XBLKS) * 256 + threadIdx.x; i < NW4; i += stride) {
            int4v w = ((const int4v*)W)[i];
            uint32_t p = ((uint32_t)(w[0] & 255)) | ((uint32_t)(w[1] & 255) << 8) |
                         ((uint32_t)(w[2] & 255) << 16) | ((uint32_t)(w[3] & 255) << 24);
            ((uint32_t*)Wq)[i] = p;
        }
    }
}

// staging: A tile = 256 rows x 64 B = 16 KB (2 issues); B tile = 128 x 64 B = 8 KB (1)
static __device__ __forceinline__ void stageA(const char* g, char* lds, int wid, size_t kb) {
    gload16(g + kb,                       lds + wid * 1024);
    gload16(g + kb + (size_t)128 * ROWB,  lds + 8192 + wid * 1024);
}
static __device__ __forceinline__ void stageB(const char* g, char* lds, int wid, size_t kb) {
    gload16(g + kb, lds + wid * 1024);
}

// ---------------- main GEMM: r10 verbatim (256x128, BK=64 i8, 3-buf) ----------------
__global__ __launch_bounds__(512, 4)
void gemm_i8(const char* __restrict__ A, const char* __restrict__ B,
             const float* __restrict__ Sx, const float* __restrict__ S,
             const float* __restrict__ Bv, float* __restrict__ Y) {
    __shared__ char smem[73728];          // A0|A1|A2 (16K each) + B0|B1|B2 (8K each)
    char* bA0 = smem;
    char* bA1 = smem + 16384;
    char* bA2 = smem + 32768;
    char* bB0 = smem + 49152;
    char* bB1 = smem + 57344;
    char* bB2 = smem + 65536;

    const int tid  = threadIdx.x;
    const int lane = tid & 63;
    const int wid  = tid >> 6;
    const int wm   = wid >> 1;            // 4 M-waves (64 rows each)
    const int wn   = wid & 1;             // 2 N-waves (64 cols each)
    const int l15  = lane & 15;
    const int q    = lane >> 4;           // k-chunk 0..3 (16 i8 each)

    // XCD-aware bijective swizzle: 688 = 8 * 86
    const int swz  = (blockIdx.x & 7) * 86 + (blockIdx.x >> 3);
    const int brow = (swz / 86) * 256;    // 8 M-tiles
    const int bcol = (swz % 86) * 128;    // 86 N-tiles

    // staging source: thread covers row tid>>2, 16-B slot (tid&3), inverse-swizzled
    const int srow4 = tid >> 2;                       // 0..127
    const int sslot = (tid & 3) ^ ((srow4 >> 1) & 3);
    const char* gA = A + (size_t)(brow + srow4) * ROWB + sslot * 16;
    const char* gB = B + (size_t)(bcol + srow4) * ROWB + sslot * 16;

    // ds_read offsets: 64-B rows; swizzled k-slot (verified 0-conflict, r7)
    const int rdA = (wm * 64 + l15) * 64;
    const int rdB = (wn * 64 + l15) * 64;
    const int kq  = (q ^ ((l15 >> 1) & 3)) * 16;

#define LDA(buf, m) (*(const int4v*)((buf) + rdA + (m) * 1024 + kq))
#define LDB(buf, n) (*(const int4v*)((buf) + rdB + (n) * 1024 + kq))

    int4v acc[4][4] = {};

    // prologue: tile0 -> buf0, tile1 -> buf1 (3 issues each); retire tile0 only
    stageA(gA, bA0, wid, 0);
    stageB(gB, bB0, wid, 0);
    stageA(gA, bA1, wid, 64);
    stageB(gB, bB1, wid, 64);
    asm volatile("s_waitcnt vmcnt(3)" ::: "memory");
    BAR();

    char* cA = bA0; char* nA = bA1; char* pA = bA2;   // cur / next / stage-target
    char* cB = bB0; char* nB = bB1; char* pB = bB2;

    for (int t = 0; t < NT; ++t) {
        const size_t kb2 = (size_t)((t + 2 < NT) ? t + 2 : NT - 1) * 64;

        int4v af[4], bf[4];
#pragma unroll
        for (int m = 0; m < 4; ++m) af[m] = LDA(cA, m);
#pragma unroll
        for (int n = 0; n < 4; ++n) bf[n] = LDB(cB, n);

        // stage tile t+2 into the 3rd buffer: its last readers were tile t-1,
        // whose ds_reads all retired before t-1's closing barrier -> no WAR.
        stageA(gA, pA, wid, kb2);
        stageB(gB, pB, wid, kb2);

        __builtin_amdgcn_s_setprio(1);
#pragma unroll
        for (int m = 0; m < 4; ++m)
#pragma unroll
            for (int n = 0; n < 4; ++n)
                acc[m][n] = __builtin_amdgcn_mfma_i32_16x16x64_i8(af[m], bf[n], acc[m][n], 0, 0, 0);
        __builtin_amdgcn_s_setprio(0);

        // retire tile t+1's 3 stages (issued last iter); keep t+2's 3 in flight
        asm volatile("s_waitcnt vmcnt(3)" ::: "memory");
        BAR();

        char* tmp;
        tmp = cA; cA = nA; nA = pA; pA = tmp;
        tmp = cB; cB = nB; nB = pB; pB = tmp;
    }

    // epilogue: y = acc * (s_r[row] * scale[col]) + bias[col]
    // C/D: col = lane&15 (+n*16), row = q*4 + r (+m*16)
#pragma unroll
    for (int n = 0; n < 4; ++n) {
        const int gc = bcol + wn * 64 + n * 16 + l15;
        const float sj = S[gc];
        const float bj = Bv[gc];
#pragma unroll
        for (int m = 0; m < 4; ++m) {
            const int grow = brow + wm * 64 + m * 16 + q * 4;
            float* yp = Y + (size_t)grow * NN + gc;
#pragma unroll
            for (int r = 0; r < 4; ++r)
                yp[(size_t)r * NN] = (float)acc[m][n][r] * (Sx[grow + r] * sj) + bj;
        }
    }
#undef LDA
#undef LDB
}

// ---------------- fallback (fused bf16 kernel, no ws needed) ----------------
#define BMF 128
#define BKF 32
#define LDW (BKF + 8)
__global__ __launch_bounds__(256, 2)
void int8lin_fused(const float* __restrict__ X, const int* __restrict__ W,
                   const float* __restrict__ S, const float* __restrict__ Bv,
                   float* __restrict__ Y) {
    __shared__ ushort As[BMF][LDW];
    __shared__ ushort Bs[BMF][LDW];
    const int tid = threadIdx.x, lane = tid & 63, wid = tid >> 6;
    const int wm = wid >> 1, wn = wid & 1, l15 = lane & 15, kh = (lane >> 4) * 8;
    const int bm = blockIdx.x & 15, bn = blockIdx.x >> 4;
    const int brow = bm * BMF, bcol = bn * BMF;
    const int srow = tid >> 1, scol = (tid & 1) * 16;
    const float* xg = X + (size_t)(brow + srow) * KK + scol;
    const int*   wg = W + (size_t)(bcol + srow) * KK + scol;
    f32x4 acc[4][4] = {};
    for (int kt = 0; kt < KK / BKF; ++kt) {
        float4v x0 = *(const float4v*)(xg + 0), x1 = *(const float4v*)(xg + 4);
        float4v x2 = *(const float4v*)(xg + 8), x3 = *(const float4v*)(xg + 12);
        int4v w0 = *(const int4v*)(wg + 0), w1 = *(const int4v*)(wg + 4);
        int4v w2 = *(const int4v*)(wg + 8), w3 = *(const int4v*)(wg + 12);
        xg += BKF; wg += BKF;
        short8 xa = { (short)f2bf_rne(x0[0]), (short)f2bf_rne(x0[1]), (short)f2bf_rne(x0[2]), (short)f2bf_rne(x0[3]),
                      (short)f2bf_rne(x1[0]), (short)f2bf_rne(x1[1]), (short)f2bf_rne(x1[2]), (short)f2bf_rne(x1[3]) };
        short8 xb = { (short)f2bf_rne(x2[0]), (short)f2bf_rne(x2[1]), (short)f2bf_rne(x2[2]), (short)f2bf_rne(x2[3]),
                      (short)f2bf_rne(x3[0]), (short)f2bf_rne(x3[1]), (short)f2bf_rne(x3[2]), (short)f2bf_rne(x3[3]) };
        short8 wa = { (short)i2bf_exact(w0[0]), (short)i2bf_exact(w0[1]), (short)i2bf_exact(w0[2]), (short)i2bf_exact(w0[3]),
                      (short)i2bf_exact(w1[0]), (short)i2bf_exact(w1[1]), (short)i2bf_exact(w1[2]), (short)i2bf_exact(w1[3]) };
        short8 wb = { (short)i2bf_exact(w2[0]), (short)i2bf_exact(w2[1]), (short)i2bf_exact(w2[2]), (short)i2bf_exact(w2[3]),
                      (short)i2bf_exact(w3[0]), (short)i2bf_exact(w3[1]), (short)i2bf_exact(w3[2]), (short)i2bf_exact(w3[3]) };
        __syncthreads();
        *(short8*)&As[srow][scol] = xa; *(short8*)&As[srow][scol + 8] = xb;
        *(short8*)&Bs[srow][scol] = wa; *(short8*)&Bs[srow][scol + 8] = wb;
        __syncthreads();
        short8 af2[4], bf4[4];
#pragma unroll
        for (int i = 0; i < 4; ++i) af2[i] = *(const short8*)&As[wm * 64 + i * 16 + l15][kh];
#pragma unroll
        for (int j = 0; j < 4; ++j) bf4[j] = *(const short8*)&Bs[wn * 64 + j * 16 + l15][kh];
#pragma unroll
        for (int i = 0; i < 4; ++i)
#pragma unroll
            for (int j = 0; j < 4; ++j)
                acc[i][j] = __builtin_amdgcn_mfma_f32_16x16x32_bf16(af2[i], bf4[j], acc[i][j], 0, 0, 0);
    }
#pragma unroll
    for (int j = 0; j < 4; ++j) {
        const int gc = bcol + wn * 64 + j * 16 + l15;
        const float sj = S[gc], bj = Bv[gc];
#pragma unroll
        for (int i = 0; i < 4; ++i) {
            const int grow = brow + wm * 64 + i * 16 + (lane >> 4) * 4;
            float* yp = Y + (size_t)grow * NN + gc;
#pragma unroll
            for (int r = 0; r < 4; ++r)
                yp[(size_t)r * NN] = acc[i][j][r] * sj + bj;
        }
    }
}

extern "C" void kernel_launch(void* const* d_in, const int* in_sizes, int n_in,
                              void* d_out, int out_size, void* d_ws, size_t ws_size,
                              hipStream_t stream) {
    const float* x = (const float*)d_in[0];
    const int*   w = (const int*)d_in[1];
    const float* s = (const float*)d_in[2];
    const float* b = (const float*)d_in[3];
    float* y = (float*)d_out;

    const size_t wq_b = (size_t)NN * KK;            // 45.1 MB
    const size_t xq_b = (size_t)MM * KK;            // 8.4 MB
    const size_t need = wq_b + xq_b + MM * sizeof(float) + 256;
    if (ws_size >= need) {
        char*  Wq = (char*)d_ws;
        char*  Xq = Wq + wq_b;
        float* Sx = (float*)(Xq + xq_b);
        hipLaunchKernelGGL(prep, dim3(PREP_XBLKS + PREP_WBLKS), dim3(256), 0, stream,
                           x, w, Sx, Xq, Wq);
        hipLaunchKernelGGL(gemm_i8, dim3((MM / 256) * (NN / 128)), dim3(512), 0, stream,
                           Xq, Wq, Sx, s, b, y);
    } else {
        hipLaunchKernelGGL(int8lin_fused, dim3((MM / BMF) * (NN / BMF)), dim3(256), 0, stream,
                           x, w, s, b, y);
    }
}